// Round 1
// 279.370 us; speedup vs baseline: 1.0072x; 1.0072x over previous
//
#include <hip/hip_runtime.h>
#include <float.h>

// VectorQuantizer: B=16,T=4096,D=256,K=1024 fp32.
// Round 3: direct-to-LDS double-buffered code staging (global_load_lds 16B,
//   XOR-swizzled source + swizzled ds_read_b128, counted vmcnt pipeline),
//   c2 folded into MFMA accumulator init (score = x.c - 0.5*c2, argmax).
//   d2 = -2*score (+x2, argmin-invariant)  =>  argmin d2 == argmax score.
//   margin-gated exact-fp32 rescue unchanged (score-space margin 0.1 == 0.2 d2).

typedef _Float16 f16;
typedef f16 f16x8 __attribute__((ext_vector_type(8)));
typedef f16 f16x4 __attribute__((ext_vector_type(4)));
typedef float f32x4 __attribute__((ext_vector_type(4)));

#define DDIM    256
#define KCODES  1024
#define NTOK    65536
#define SMARGIN 0.1f   // score-space margin; == 0.2 in d2 units since d2 gap = 2*score gap

typedef const __attribute__((address_space(1))) void gv_t;
typedef __attribute__((address_space(3))) void lv_t;

// ---------------- prep: codebook fp32->f16, c2, zero counter ----------------
__global__ __launch_bounds__(256) void vq_prep(const float* __restrict__ cb,
                                               f16* __restrict__ ch,
                                               float* __restrict__ c2,
                                               unsigned* __restrict__ count) {
    const int k    = blockIdx.x * 4 + (threadIdx.x >> 6);
    const int lane = threadIdx.x & 63;
    const float4 v = *(const float4*)(cb + (size_t)k * DDIM + 4 * lane);
    f16x4 h; h[0] = (f16)v.x; h[1] = (f16)v.y; h[2] = (f16)v.z; h[3] = (f16)v.w;
    *(f16x4*)(ch + (size_t)k * DDIM + 4 * lane) = h;
    float s = v.x * v.x + v.y * v.y + v.z * v.z + v.w * v.w;
    #pragma unroll
    for (int off = 32; off > 0; off >>= 1) s += __shfl_down(s, off, 64);
    if (lane == 0) c2[k] = s;
    if (blockIdx.x == 0 && threadIdx.x == 0) *count = 0u;
}

// ---------------- main: MFMA distances + fused argmax(score) + gather ----------------
// Stage tile: 128 code rows x 64 f16 (128 B/row), linear LDS, double-buffered.
// LDS linear slot (r, cb) holds global element (r, cb ^ ((r&7)<<4))  [XOR involution]
//   -> stage: per-lane global col byte = 16*((lane&7) ^ (lane>>3)); dest linear.
//   -> read : byte = R*128 + ((kk*64 | q*16) ^ ((R&7)<<4)); bank-uniform (2-way only).
#define STAGE(S, BUF) do {                                                          \
    const int nc_ = (S) >> 2, st_ = (S) & 3;                                        \
    char* ldsb_ = (char*)As + (BUF) * 16384 + wave * 4096;                          \
    const char* gsrc_ = chb + (size_t)(nc_ * 128 + wave * 32 + (lane >> 3)) * 512   \
                        + st_ * 128 + srccb;                                        \
    _Pragma("unroll")                                                               \
    for (int i_ = 0; i_ < 4; ++i_)                                                  \
        __builtin_amdgcn_global_load_lds((gv_t*)(gsrc_ + i_ * 4096),                \
                                         (lv_t*)(ldsb_ + i_ * 1024), 16, 0, 0);     \
} while (0)

__global__ __launch_bounds__(256, 2) void vq_main(const float* __restrict__ xg,
                                                  const f16* __restrict__ ch,
                                                  const float* __restrict__ c2,
                                                  const float* __restrict__ cb,
                                                  float* __restrict__ out,
                                                  unsigned* __restrict__ count,
                                                  unsigned* __restrict__ list) {
    __shared__ f16   As[2 * 8192];             // 2 x (128 x 64) f16 = 32 KB, linear
    __shared__ float c2s[KCODES];              // c2 staged once (keeps loop VMEM = staging only)
    __shared__ float wmv[2][128];              // per code-half best score
    __shared__ int   wmi[2][128];
    __shared__ float wms[2][128];              // per code-half second score
    __shared__ float runv[128], runs[128];
    __shared__ int   runi[128];
    __shared__ int   idx_s[128];

    const int t    = threadIdx.x;
    const int wave = t >> 6, lane = t & 63;
    const int wm   = wave >> 1;                // code-half (M)
    const int tn   = wave & 1;                 // token-half (N)
    const int q    = lane >> 4;                // operand quad
    const int m16  = lane & 15;
    const int tok0 = blockIdx.x * 128;
    const char* chb = (const char*)ch;
    const int srccb = 16 * ((lane & 7) ^ (lane >> 3));  // stage-side source swizzle
    const int swz   = (m16 & 7) << 4;                   // read-side swizzle

    // ---- load token B-fragments, fp32 -> f16 in registers (once) ----
    // B[n = lane&15][k], k-global = ks*32 + q*8 + j. Converts consume the loads
    // immediately, so no token-load vmem is outstanding at loop entry.
    f16x8 bfrag[4][8];
    #pragma unroll
    for (int ti = 0; ti < 4; ++ti) {
        const size_t row = (size_t)(tok0 + tn * 64 + ti * 16 + m16) * DDIM;
        #pragma unroll
        for (int ks = 0; ks < 8; ++ks) {
            const float* p = xg + row + ks * 32 + q * 8;
            const float4 u0 = *(const float4*)(p);
            const float4 u1 = *(const float4*)(p + 4);
            f16x8 b;
            b[0] = (f16)u0.x; b[1] = (f16)u0.y; b[2] = (f16)u0.z; b[3] = (f16)u0.w;
            b[4] = (f16)u1.x; b[5] = (f16)u1.y; b[6] = (f16)u1.z; b[7] = (f16)u1.w;
            bfrag[ti][ks] = b;
        }
    }

    *(float4*)&c2s[t * 4] = *(const float4*)(c2 + t * 4);   // 1024 floats
    if (t < 128) { runv[t] = -FLT_MAX; runs[t] = -FLT_MAX; runi[t] = 0; }

    STAGE(0, 0);
    __syncthreads();                           // full drain: stage0 + c2s + init visible

    f32x4 acc[4][4];                           // [ci][ti]
    for (int s = 0; s < 32; ++s) {             // 8 chunks x 4 stages (BK=64)
        const int nc = s >> 2, st = s & 3;
        if (st == 0) {                         // acc init = -0.5*c2  (score space)
            #pragma unroll
            for (int ci = 0; ci < 4; ++ci) {
                f32x4 cv = *(const f32x4*)&c2s[nc * 128 + wm * 64 + ci * 16 + q * 4];
                cv = cv * -0.5f;
                #pragma unroll
                for (int ti = 0; ti < 4; ++ti) acc[ci][ti] = cv;
            }
        }
        __builtin_amdgcn_s_barrier();          // B1: all readers of buf[(s+1)&1] done
        if (s < 31) {
            STAGE(s + 1, (s + 1) & 1);         // prefetch next stage (4 loads in flight)
            asm volatile("s_waitcnt vmcnt(4)" ::: "memory");  // my stage(s) retired
        } else {
            asm volatile("s_waitcnt vmcnt(0)" ::: "memory");
        }
        __builtin_amdgcn_s_barrier();          // B2: everyone's stage(s) in LDS
        __builtin_amdgcn_sched_barrier(0);     // pin ds_reads below B2 (rule #18)

        const char* Ab = (const char*)As + (s & 1) * 16384;
        const int rbase = (wm * 64 + m16) * 128;
        #pragma unroll
        for (int kk = 0; kk < 2; ++kk) {
            const int col = ((kk << 6) | (q << 4)) ^ swz;
            f16x8 af[4];
            #pragma unroll
            for (int ci = 0; ci < 4; ++ci)
                af[ci] = *(const f16x8*)(Ab + rbase + ci * 2048 + col);
            const int ksg = st * 2 + kk;
            #pragma unroll
            for (int ci = 0; ci < 4; ++ci)
                #pragma unroll
                for (int ti = 0; ti < 4; ++ti)
                    acc[ci][ti] = __builtin_amdgcn_mfma_f32_16x16x32_f16(
                        af[ci], bfrag[ti][ksg], acc[ci][ti], 0, 0, 0);
        }

        if (st == 3) {
            // ---- chunk epilogue: per-token top-2 (max score) over 128 codes ----
            const int kbase = nc * 128 + wm * 64;
            #pragma unroll
            for (int ti = 0; ti < 4; ++ti) {
                float b1 = -FLT_MAX, b2 = -FLT_MAX; int i1 = 0;
                #pragma unroll
                for (int ci = 0; ci < 4; ++ci) {   // ascending code order within lane
                    #pragma unroll
                    for (int r = 0; r < 4; ++r) {
                        const float v = acc[ci][ti][r];
                        const int   c = kbase + ci * 16 + q * 4 + r;
                        const bool gt = v > b1;    // strict: tie keeps lower index
                        b2 = fmaxf(b2, gt ? b1 : v);
                        i1 = gt ? c : i1;
                        b1 = gt ? v : b1;
                    }
                }
                // merge across the 4 quads (lanes l^16, l^32 share token)
                #pragma unroll
                for (int sft = 0; sft < 2; ++sft) {
                    const int off = 16 << sft;
                    const float ob1 = __shfl_xor(b1, off, 64);
                    const float ob2 = __shfl_xor(b2, off, 64);
                    const int   oi1 = __shfl_xor(i1, off, 64);
                    const bool better = (ob1 > b1) || (ob1 == b1 && oi1 < i1);
                    b2 = fmaxf(fmaxf(b2, ob2), fminf(b1, ob1));
                    b1 = better ? ob1 : b1;
                    i1 = better ? oi1 : i1;
                }
                if (lane < 16) {
                    const int tl = tn * 64 + ti * 16 + m16;
                    wmv[wm][tl] = b1; wmi[wm][tl] = i1; wms[wm][tl] = b2;
                }
            }
            __syncthreads();
            if (t < 128) {                      // merge code-halves, fold into running
                const float a1 = wmv[0][t], a2 = wms[0][t];
                const int   ai = wmi[0][t];
                const float b1_ = wmv[1][t], b2_ = wms[1][t];
                const int   bi_ = wmi[1][t];
                const bool bb = (b1_ > a1) || (b1_ == a1 && bi_ < ai);
                const float c1 = bb ? b1_ : a1;
                const int   ci_ = bb ? bi_ : ai;
                const float cs = fmaxf(fmaxf(a2, b2_), fminf(a1, b1_));
                const float r1 = runv[t];
                runs[t] = fmaxf(fmaxf(runs[t], cs), fminf(r1, c1));
                if (c1 > r1) { runv[t] = c1; runi[t] = ci_; }  // tie -> earlier chunk wins
            }
            // next iteration's B1 orders the wmv rewrite
        }
    }

    __syncthreads();
    if (t < 128) {
        idx_s[t] = runi[t];
        if (runv[t] - runs[t] < SMARGIN) {      // d2 gap = 2*(runv-runs) < 0.2
            const unsigned p = atomicAdd(count, 1u);
            list[p] = tok0 + t;
        }
    }
    __syncthreads();

    // gather epilogue: out[tok] = cb[argmin], coalesced float4
    #pragma unroll
    for (int i = 0; i < 32; ++i) {
        const int f   = i * 256 + t;           // 8192 float4 = 128 tok x 64
        const int tok = f >> 6, d4 = f & 63;
        const int code = idx_s[tok];
        const float4 v = *(const float4*)(cb + (size_t)code * DDIM + 4 * d4);
        *(float4*)(out + (size_t)(tok0 + tok) * DDIM + 4 * d4) = v;
    }
}

// ---------------- rescue: exact fp32 argmin for margin-flagged tokens ----------------
__global__ __launch_bounds__(256) void vq_rescue(const float* __restrict__ xg,
                                                 const float* __restrict__ cb,
                                                 const float* __restrict__ c2,
                                                 const unsigned* __restrict__ count,
                                                 const unsigned* __restrict__ list,
                                                 float* __restrict__ out) {
    __shared__ float xls[8][DDIM];
    __shared__ float rv[4];
    __shared__ int   ri[4];
    __shared__ int   bidx[8];

    const int t = threadIdx.x;
    const int wave = t >> 6, lane = t & 63;
    const unsigned n = *count;

    for (unsigned base = blockIdx.x * 8; base < n; base += gridDim.x * 8) {
        const int nb = (int)min(8u, n - base);
        __syncthreads();
        #pragma unroll
        for (int i = 0; i < 2; ++i) {
            const int f = t + 256 * i;          // 512 float4 slots
            const int row = f >> 6, d4 = f & 63;
            if (row < nb)
                *(float4*)&xls[row][4 * d4] =
                    *(const float4*)(xg + (size_t)list[base + row] * DDIM + 4 * d4);
        }
        __syncthreads();

        float acc[4][8];
        #pragma unroll
        for (int j = 0; j < 4; ++j)
            #pragma unroll
            for (int tk = 0; tk < 8; ++tk) acc[j][tk] = 0.0f;

        for (int d4 = 0; d4 < 64; ++d4) {
            float4 xv[8];
            #pragma unroll
            for (int tk = 0; tk < 8; ++tk) xv[tk] = *(const float4*)&xls[tk][4 * d4];
            #pragma unroll
            for (int j = 0; j < 4; ++j) {
                const float4 cv = *(const float4*)(cb + (size_t)(4 * t + j) * DDIM + 4 * d4);
                #pragma unroll
                for (int tk = 0; tk < 8; ++tk) {
                    // sequential .x->.w accumulation: matches round-1-verified order
                    float a = acc[j][tk];
                    a = fmaf(cv.x, xv[tk].x, a);
                    a = fmaf(cv.y, xv[tk].y, a);
                    a = fmaf(cv.z, xv[tk].z, a);
                    a = fmaf(cv.w, xv[tk].w, a);
                    acc[j][tk] = a;
                }
            }
        }

        for (int tk = 0; tk < nb; ++tk) {
            float b1 = FLT_MAX; int i1 = 0;
            #pragma unroll
            for (int j = 0; j < 4; ++j) {       // codes 4t..4t+3 ascending
                const float d = fmaf(-2.0f, acc[j][tk], c2[4 * t + j]);
                if (d < b1) { b1 = d; i1 = 4 * t + j; }
            }
            #pragma unroll
            for (int off = 32; off > 0; off >>= 1) {
                const float ov = __shfl_xor(b1, off, 64);
                const int   oi = __shfl_xor(i1, off, 64);
                if (ov < b1 || (ov == b1 && oi < i1)) { b1 = ov; i1 = oi; }
            }
            if (lane == 0) { rv[wave] = b1; ri[wave] = i1; }
            __syncthreads();
            if (t == 0) {
                float bv = rv[0]; int bi = ri[0];
                #pragma unroll
                for (int w = 1; w < 4; ++w)
                    if (rv[w] < bv || (rv[w] == bv && ri[w] < bi)) { bv = rv[w]; bi = ri[w]; }
                bidx[tk] = bi;
            }
            __syncthreads();
        }

        #pragma unroll
        for (int i = 0; i < 2; ++i) {
            const int f = t + 256 * i;
            const int row = f >> 6, d4 = f & 63;
            if (row < nb) {
                const int code = bidx[row];
                const float4 v = *(const float4*)(cb + (size_t)code * DDIM + 4 * d4);
                *(float4*)(out + (size_t)list[base + row] * DDIM + 4 * d4) = v;
            }
        }
    }
}

extern "C" void kernel_launch(void* const* d_in, const int* in_sizes, int n_in,
                              void* d_out, int out_size, void* d_ws, size_t ws_size,
                              hipStream_t stream) {
    const float* x  = (const float*)d_in[0];   // [B,T,D] fp32
    const float* cb = (const float*)d_in[1];   // [K,D]   fp32
    float* out = (float*)d_out;

    char* ws = (char*)d_ws;
    f16*      ch    = (f16*)ws;                              // 524288 B
    float*    c2    = (float*)(ws + 524288);                 // 4096 B
    unsigned* count = (unsigned*)(ws + 528448);              // 4 B (padded)
    unsigned* list  = (unsigned*)(ws + 528512);              // 262144 B

    hipLaunchKernelGGL(vq_prep,   dim3(KCODES / 4), dim3(256), 0, stream, cb, ch, c2, count);
    hipLaunchKernelGGL(vq_main,   dim3(NTOK / 128), dim3(256), 0, stream,
                       x, ch, c2, cb, out, count, list);
    hipLaunchKernelGGL(vq_rescue, dim3(256),        dim3(256), 0, stream,
                       x, cb, c2, count, list, out);
}